// Round 3
// baseline (221.277 us; speedup 1.0000x reference)
//
#include <hip/hip_runtime.h>
#include <cstddef>

#define D   64
#define L   128
#define NT  256            // 4 waves per block
#define TR  16             // rows per stream tile (one M=16 MFMA tile)
#define ROWS 32            // 2 independent streams x 16 rows per block
#define XSS 132            // padded floats (mult of 4 keeps float4 alignment)
#define HBS 72             // shorts
#define NBLK 256           // 8192 / 32
#define LOG2E 1.4426950408889634f

typedef __attribute__((ext_vector_type(8))) short short8;
typedef __attribute__((ext_vector_type(4))) float floatx4;
typedef __attribute__((ext_vector_type(2))) float f2;

__device__ __forceinline__ float fast_rcp(float x) {
#if defined(__has_builtin)
#if __has_builtin(__builtin_amdgcn_rcpf)
  return __builtin_amdgcn_rcpf(x);
#else
  return 1.0f / x;
#endif
#else
  return 1.0f / x;
#endif
}
__device__ __forceinline__ float ex2(float x) {
#if defined(__has_builtin)
#if __has_builtin(__builtin_amdgcn_exp2f)
  return __builtin_amdgcn_exp2f(x);
#else
  return __builtin_exp2f(x);
#endif
#else
  return __builtin_exp2f(x);
#endif
}
__device__ __forceinline__ f2 ex2_2(f2 v) { return (f2){ex2(v.x), ex2(v.y)}; }
__device__ __forceinline__ f2 rcp_2(f2 v) { return (f2){fast_rcp(v.x), fast_rcp(v.y)}; }
__device__ __forceinline__ float sig_plain(float x) {
  return fast_rcp(1.0f + ex2(-LOG2E * x));
}
__device__ __forceinline__ float tanh2(float G) {   // tanh(x), G = -2log2e*x
  return fmaf(2.0f, fast_rcp(1.0f + ex2(G)), -1.0f);
}
__device__ __forceinline__ unsigned short f2bf_rtne(float f) {
  unsigned int u = __float_as_uint(f);
  u += 0x7fffu + ((u >> 16) & 1u);
  return (unsigned short)(u >> 16);
}

// R14: in-wave 2-stream software pipeline.
// R12 measured a single stream's exposed chain stall at ~1700cyc/step;
// R11's scheduler-provided second stream (co-resident block) recovered
// only ~860 of it (phase-lock), and R13's stagger attempt was confounded
// by codegen (spills). Fix: internalize the second stream. Each block
// owns 32 rows = two independent 16-row streams A/B; each wave processes
// both in fixed program order per step:
//   readA, readB -> mfmaA -> ewA -> writeA -> mfmaB -> ewB -> writeB -> bar
// A's stalls are covered by B's guaranteed-issuable instructions in the
// SAME wave (compiler-ordered, scheduler-independent), and one barrier
// now serves both streams' steps. Weights (Bf/An/Bc) shared between
// streams -> only ~+25 VGPR. Grid: 256 blocks x 4 waves = 1024 waves =
// 1/SIMD, 1 block/CU. Per-stream math/op-order identical to R11 ->
// bit-identical results (absmax must stay 8.0).
__global__ __launch_bounds__(NT, 1)
void lstm_main(const float* __restrict__ x,
               const float* __restrict__ W_num,
               const float* __restrict__ b_num,
               const float* __restrict__ W_ih,
               const float* __restrict__ W_hh,
               const float* __restrict__ b_ih,
               const float* __restrict__ b_hh,
               const float* __restrict__ W_aout,
               const float* __restrict__ b_aout,
               const float* __restrict__ W_fh,
               const float* __restrict__ b_fh,
               const float* __restrict__ W_iouh,
               const float* __restrict__ b_iouh,
               const float* __restrict__ W_oout,
               const float* __restrict__ b_oout,
               float* __restrict__ acc_out,   // [0..63]=fc, [64..127]=hs, [128]=ticket
               float* __restrict__ out)
{
  __shared__ __align__(16) float xs[ROWS * XSS];        // 16.5 KB (x; later h/h_hat)
  __shared__ __align__(16) short hb[2][2][TR * HBS];    // [stream][phase] bf16 h, 9 KB
  __shared__ float sacc[2 * D];
  __shared__ float hobj[D];
  __shared__ int   is_last;

  const int tid  = threadIdx.x;
  const int w    = tid >> 6;
  const int lane = tid & 63;
  const int quad = lane >> 4;
  const int c16  = lane & 15;
  const int k0   = blockIdx.x * ROWS;
  const int dcol = w * 16 + c16;

  // ---- stage x tile (32 rows x 128), coalesced ----
  for (int i = tid; i < ROWS * (L / 4); i += NT) {
    int r = i >> 5, c4 = i & 31;
    float4 v = ((const float4*)(x + (size_t)(k0 + r) * L))[c4];
    float* dst = &xs[r * XSS + c4 * 4];
    dst[0] = v.x; dst[1] = v.y; dst[2] = v.z; dst[3] = v.w;
  }
  for (int i = tid; i < 2 * 2 * TR * HBS; i += NT) ((short*)hb)[i] = 0;

  // per-gate exp2 prescale (g-gate feeds tanh -> -2log2e)
  const float gscale[4] = {-LOG2E, -LOG2E, -2.0f * LOG2E, -LOG2E};

  // ---- rank-1 x-projection constants (prescaled), float4 loads ----
  float An[4], Bc[4];
#pragma unroll
  for (int g = 0; g < 4; ++g) {
    int j = g * 64 + dcol;
    const float4* wr = (const float4*)(W_ih + (size_t)j * (2 * D));
    float a = 0.0f, b = b_ih[j] + b_hh[j];
#pragma unroll
    for (int e4 = 0; e4 < 16; ++e4) {
      float4 wv = wr[e4];
      float4 wn = ((const float4*)W_num)[e4];
      float4 bn = ((const float4*)b_num)[e4];
      a = fmaf(wn.x, wv.x, a); a = fmaf(wn.y, wv.y, a);
      a = fmaf(wn.z, wv.z, a); a = fmaf(wn.w, wv.w, a);
      b = fmaf(bn.x, wv.x, b); b = fmaf(bn.y, wv.y, b);
      b = fmaf(bn.z, wv.z, b); b = fmaf(bn.w, wv.w, b);
    }
    An[g] = a * gscale[g]; Bc[g] = b * gscale[g];
  }

  // ---- W_hh B-fragments (prescaled, single RTNE bf16, constant) ----
  short8 Bf[4][2];
#pragma unroll
  for (int g = 0; g < 4; ++g) {
#pragma unroll
    for (int kk = 0; kk < 2; ++kk) {
      const float4* wp = (const float4*)(W_hh + (size_t)(g * 64 + dcol) * D
                                         + kk * 32 + quad * 8);
      float wv[8];
      float4 w0 = wp[0], w1 = wp[1];
      wv[0]=w0.x; wv[1]=w0.y; wv[2]=w0.z; wv[3]=w0.w;
      wv[4]=w1.x; wv[5]=w1.y; wv[6]=w1.z; wv[7]=w1.w;
      short8 hi8;
#pragma unroll
      for (int j = 0; j < 8; ++j)
        hi8[j] = (short)f2bf_rtne(wv[j] * gscale[g]);
      Bf[g][kk] = hi8;
    }
  }

  const f2 one2  = {1.0f, 1.0f};
  const f2 m2l2  = {-2.0f * LOG2E, -2.0f * LOG2E};
  f2 cregA[2] = {{0.f, 0.f}, {0.f, 0.f}};   // stream A cell pairs
  f2 hregA[2] = {{0.f, 0.f}, {0.f, 0.f}};
  f2 cregB[2] = {{0.f, 0.f}, {0.f, 0.f}};   // stream B
  f2 hregB[2] = {{0.f, 0.f}, {0.f, 0.f}};
  __syncthreads();

  // one stream's step: init from x, 8 MFMAs, merged elementwise, write h
  auto cell_step = [&](const short8 ahi[2], f2 creg2[2], f2 hreg2[2],
                       f2 xv01, f2 xv23, short* hbw) {
    floatx4 acc[4];
#pragma unroll
    for (int g = 0; g < 4; ++g) {
      f2 A2 = {An[g], An[g]}, B2 = {Bc[g], Bc[g]};
      f2 i01 = A2 * xv01 + B2;        // v_pk_fma_f32
      f2 i23 = A2 * xv23 + B2;
      acc[g] = (floatx4){i01.x, i01.y, i23.x, i23.y};
    }
#pragma unroll
    for (int kk = 0; kk < 2; ++kk) {
#pragma unroll
      for (int g = 0; g < 4; ++g)
        acc[g] = __builtin_amdgcn_mfma_f32_16x16x32_bf16(ahi[kk], Bf[g][kk], acc[g], 0, 0, 0);
    }
#pragma unroll
    for (int h = 0; h < 2; ++h) {
      f2 Gi = {acc[0][2*h], acc[0][2*h+1]};
      f2 Gf = {acc[1][2*h], acc[1][2*h+1]};
      f2 Gg = {acc[2][2*h], acc[2][2*h+1]};
      f2 Go = {acc[3][2*h], acc[3][2*h+1]};
      f2 Ei = ex2_2(Gi), Ef = ex2_2(Gf), Eg = ex2_2(Gg), Eo = ex2_2(Go);
      f2 pf = Ef + one2, pi = Ei + one2, pg = Eg + one2, mg = one2 - Eg;
      f2 pig = pi * pg;
      f2 num = creg2[h] * pig + mg * pf;
      f2 c2  = num * rcp_2(pf * pig);
      creg2[h] = c2;
      f2 Ec = ex2_2(c2 * m2l2);
      f2 po = Eo + one2, pc = Ec + one2, mc = one2 - Ec;
      f2 h2 = mc * rcp_2(po * pc);
      hreg2[h] = h2;
      int row0 = quad * 4 + 2 * h;
      hbw[row0 * HBS + dcol]       = (short)f2bf_rtne(h2.x);
      hbw[(row0 + 1) * HBS + dcol] = (short)f2bf_rtne(h2.y);
    }
  };

  int p = 0;
  for (int t4 = 0; t4 < L; t4 += 4) {
    // 4 steps' worth of x per row in one b128 each, both streams
    float4 xqA[4], xqB[4];
#pragma unroll
    for (int r = 0; r < 4; ++r) {
      xqA[r] = *(const float4*)&xs[(quad * 4 + r) * XSS + t4];
      xqB[r] = *(const float4*)&xs[(TR + quad * 4 + r) * XSS + t4];
    }
#pragma unroll
    for (int u = 0; u < 4; ++u) {
      // both streams' A-fragments of h(t-1) issued up-front:
      // mfmaA only needs lgkmcnt(2) (B's reads still in flight)
      short8 aA[2], aB[2];
#pragma unroll
      for (int kk = 0; kk < 2; ++kk)
        aA[kk] = *(const short8*)&hb[0][p][c16 * HBS + kk * 32 + quad * 8];
#pragma unroll
      for (int kk = 0; kk < 2; ++kk)
        aB[kk] = *(const short8*)&hb[1][p][c16 * HBS + kk * 32 + quad * 8];

      f2 xA01 = {xqA[0][u], xqA[1][u]};
      f2 xA23 = {xqA[2][u], xqA[3][u]};
      cell_step(aA, cregA, hregA, xA01, xA23, &hb[0][p ^ 1][0]);

      f2 xB01 = {xqB[0][u], xqB[1][u]};
      f2 xB23 = {xqB[2][u], xqB[3][u]};
      cell_step(aB, cregB, hregB, xB01, xB23, &hb[1][p ^ 1][0]);

      __syncthreads();
      p ^= 1;
    }
  }

  // unpack pair registers for the tail
  float creg[2][4] = {{cregA[0].x, cregA[0].y, cregA[1].x, cregA[1].y},
                      {cregB[0].x, cregB[0].y, cregB[1].x, cregB[1].y}};
  float hreg[2][4] = {{hregA[0].x, hregA[0].y, hregA[1].x, hregA[1].y},
                      {hregB[0].x, hregB[0].y, hregB[1].x, hregB[1].y}};

  // ---- tail: h_hat = h@W_aout.T+b ; f = h_hat@W_fh.T+b ; partial sums ----
  // x tile dead: xs[row][0..63] = h fp32, xs[row][64..127] = h_hat
#pragma unroll
  for (int s = 0; s < 2; ++s)
#pragma unroll
    for (int r = 0; r < 4; ++r)
      xs[(s * TR + quad * 4 + r) * XSS + dcol] = hreg[s][r];
  __syncthreads();

  float hhat[2][4];
#pragma unroll
  for (int s = 0; s < 2; ++s) {
#pragma unroll
    for (int r = 0; r < 4; ++r) {
      float a = b_aout[dcol];
      const float4* wa = (const float4*)(W_aout + (size_t)dcol * D);
      const float* hp = &xs[(s * TR + quad * 4 + r) * XSS];
#pragma unroll
      for (int e4 = 0; e4 < 16; ++e4) {
        float4 wv = wa[e4];
        a = fmaf(wv.x, hp[e4*4+0], a); a = fmaf(wv.y, hp[e4*4+1], a);
        a = fmaf(wv.z, hp[e4*4+2], a); a = fmaf(wv.w, hp[e4*4+3], a);
      }
      hhat[s][r] = a;
    }
  }
  __syncthreads();
#pragma unroll
  for (int s = 0; s < 2; ++s)
#pragma unroll
    for (int r = 0; r < 4; ++r)
      xs[(s * TR + quad * 4 + r) * XSS + 64 + dcol] = hhat[s][r];
  __syncthreads();

  float pfc = 0.0f, phs = 0.0f;
#pragma unroll
  for (int s = 0; s < 2; ++s) {
#pragma unroll
    for (int r = 0; r < 4; ++r) {
      float f = b_fh[dcol];
      const float4* wf = (const float4*)(W_fh + (size_t)dcol * D);
      const float* hp = &xs[(s * TR + quad * 4 + r) * XSS + 64];
#pragma unroll
      for (int e4 = 0; e4 < 16; ++e4) {
        float4 wv = wf[e4];
        f = fmaf(wv.x, hp[e4*4+0], f); f = fmaf(wv.y, hp[e4*4+1], f);
        f = fmaf(wv.z, hp[e4*4+2], f); f = fmaf(wv.w, hp[e4*4+3], f);
      }
      pfc = fmaf(sig_plain(f), creg[s][r], pfc);
      phs += hhat[s][r];
    }
  }
  pfc += __shfl_xor(pfc, 16); pfc += __shfl_xor(pfc, 32);
  phs += __shfl_xor(phs, 16); phs += __shfl_xor(phs, 32);
  if (quad == 0) {
    atomicAdd(acc_out + dcol, pfc);
    atomicAdd(acc_out + D + dcol, phs);
  }

  // ---- last-block finish ----
  __threadfence();
  if (tid == 0) {
    unsigned int prev = __hip_atomic_fetch_add((unsigned int*)(acc_out + 2 * D), 1u,
                                               __ATOMIC_ACQ_REL, __HIP_MEMORY_SCOPE_AGENT);
    is_last = (prev == NBLK - 1) ? 1 : 0;
  }
  __syncthreads();
  if (!is_last) return;
  __threadfence();
  if (tid < 2 * D)
    sacc[tid] = __hip_atomic_load(acc_out + tid, __ATOMIC_RELAXED, __HIP_MEMORY_SCOPE_AGENT);
  __syncthreads();
  if (tid < D) {
    const int d = tid;
    float vi = b_iouh[d], vo = b_iouh[D + d], vu = b_iouh[2 * D + d];
    for (int e = 0; e < D; ++e) {
      float hs = sacc[D + e];
      vi = fmaf(W_iouh[(size_t)d * D + e],           hs, vi);
      vo = fmaf(W_iouh[(size_t)(D + d) * D + e],     hs, vo);
      vu = fmaf(W_iouh[(size_t)(2 * D + d) * D + e], hs, vu);
    }
    float c_obj = sig_plain(vi) * tanh2(-2.0f * LOG2E * vu) + sacc[d];
    float h_obj = sig_plain(vo) * tanh2(-2.0f * LOG2E * c_obj);
    hobj[d] = h_obj;
    out[D + d] = c_obj;
  }
  __syncthreads();
  if (tid < D) {
    const int d = tid;
    float hh = b_oout[d];
    for (int e = 0; e < D; ++e) hh = fmaf(W_oout[(size_t)d * D + e], hobj[e], hh);
    out[d] = hh;
  }
}

extern "C" void kernel_launch(void* const* d_in, const int* in_sizes, int n_in,
                              void* d_out, int out_size, void* d_ws, size_t ws_size,
                              hipStream_t stream) {
  const float* x      = (const float*)d_in[0];
  const float* W_num  = (const float*)d_in[1];
  const float* b_num  = (const float*)d_in[2];
  const float* W_ih   = (const float*)d_in[3];
  const float* W_hh   = (const float*)d_in[4];
  const float* b_ih   = (const float*)d_in[5];
  const float* b_hh   = (const float*)d_in[6];
  const float* W_aout = (const float*)d_in[7];
  const float* b_aout = (const float*)d_in[8];
  const float* W_fh   = (const float*)d_in[9];
  const float* b_fh   = (const float*)d_in[10];
  const float* W_iouh = (const float*)d_in[11];
  const float* b_iouh = (const float*)d_in[12];
  const float* W_oout = (const float*)d_in[13];
  const float* b_oout = (const float*)d_in[14];
  float* acc = (float*)d_ws;
  float* out = (float*)d_out;

  hipMemsetAsync(d_ws, 0, (2 * D + 1) * sizeof(float), stream);
  lstm_main<<<NBLK, NT, 0, stream>>>(x, W_num, b_num, W_ih, W_hh, b_ih, b_hh,
                                     W_aout, b_aout, W_fh, b_fh,
                                     W_iouh, b_iouh, W_oout, b_oout, acc, out);
}

// Round 4
// 219.960 us; speedup vs baseline: 1.0060x; 1.0060x over previous
//
#include <hip/hip_runtime.h>
#include <cstddef>

#define D   64
#define L   128
#define NT  256            // 4 waves per block
#define TR  16             // rows per stream tile (one M=16 MFMA tile)
#define ROWS 32            // 2 independent streams x 16 rows per block
#define XSS 132            // padded floats (mult of 4 keeps float4 alignment)
#define HBS 72             // shorts
#define NBLK 256           // 8192 / 32
#define LOG2E 1.4426950408889634f

typedef __attribute__((ext_vector_type(8))) short short8;
typedef __attribute__((ext_vector_type(4))) float floatx4;
typedef __attribute__((ext_vector_type(2))) float f2;
typedef __attribute__((ext_vector_type(4))) float f4;

__device__ __forceinline__ float fast_rcp(float x) {
#if defined(__has_builtin)
#if __has_builtin(__builtin_amdgcn_rcpf)
  return __builtin_amdgcn_rcpf(x);
#else
  return 1.0f / x;
#endif
#else
  return 1.0f / x;
#endif
}
__device__ __forceinline__ float ex2(float x) {
#if defined(__has_builtin)
#if __has_builtin(__builtin_amdgcn_exp2f)
  return __builtin_amdgcn_exp2f(x);
#else
  return __builtin_exp2f(x);
#endif
#else
  return __builtin_exp2f(x);
#endif
}
__device__ __forceinline__ f4 ex2_4(f4 v) {
  return (f4){ex2(v.x), ex2(v.y), ex2(v.z), ex2(v.w)};
}
__device__ __forceinline__ f4 rcp_4(f4 v) {
  return (f4){fast_rcp(v.x), fast_rcp(v.y), fast_rcp(v.z), fast_rcp(v.w)};
}
__device__ __forceinline__ float sig_plain(float x) {
  return fast_rcp(1.0f + ex2(-LOG2E * x));
}
__device__ __forceinline__ float tanh2(float G) {   // tanh(x), G = -2log2e*x
  return fmaf(2.0f, fast_rcp(1.0f + ex2(G)), -1.0f);
}
__device__ __forceinline__ unsigned short f2bf_rtne(float f) {
  unsigned int u = __float_as_uint(f);
  u += 0x7fffu + ((u >> 16) & 1u);
  return (unsigned short)(u >> 16);
}

// R15: R14's in-wave 2-stream structure, but the A/B interleave is now
// FORCED by SLP-vectorizing the two streams into f4 (4-wide ext-vector)
// elementwise: Gi = {A.lo, A.hi, B.lo, B.hi}. R14 post-mortem: compiler
// kept the two scalar chains sequential (VGPR stayed at 96 = pressure-
// minimizing schedule; VALUBusy 45% not 65+; wall/step ~ issue + full
// chain stall). With f4, every arith step is 2 independent v_pk ops and
// every trans step is 4 independent v_exp/v_rcp -> cross-stream
// interleave is encoded in the instruction stream, not left to the
// scheduler. MFMAs alternate A/B per gate (per-acc order unchanged).
// Each scalar op elementwise-identical to R14 -> bit-identical results
// (absmax must stay 8.0). Grid: 256 blocks x 4 waves = 1 wave/SIMD,
// 1 block/CU; VGPR free to grow (no occupancy cliff until 512).
__global__ __launch_bounds__(NT, 1)
void lstm_main(const float* __restrict__ x,
               const float* __restrict__ W_num,
               const float* __restrict__ b_num,
               const float* __restrict__ W_ih,
               const float* __restrict__ W_hh,
               const float* __restrict__ b_ih,
               const float* __restrict__ b_hh,
               const float* __restrict__ W_aout,
               const float* __restrict__ b_aout,
               const float* __restrict__ W_fh,
               const float* __restrict__ b_fh,
               const float* __restrict__ W_iouh,
               const float* __restrict__ b_iouh,
               const float* __restrict__ W_oout,
               const float* __restrict__ b_oout,
               float* __restrict__ acc_out,   // [0..63]=fc, [64..127]=hs, [128]=ticket
               float* __restrict__ out)
{
  __shared__ __align__(16) float xs[ROWS * XSS];        // 16.5 KB (x; later h/h_hat)
  __shared__ __align__(16) short hb[2][2][TR * HBS];    // [stream][phase] bf16 h, 9 KB
  __shared__ float sacc[2 * D];
  __shared__ float hobj[D];
  __shared__ int   is_last;

  const int tid  = threadIdx.x;
  const int w    = tid >> 6;
  const int lane = tid & 63;
  const int quad = lane >> 4;
  const int c16  = lane & 15;
  const int k0   = blockIdx.x * ROWS;
  const int dcol = w * 16 + c16;

  // ---- stage x tile (32 rows x 128), coalesced ----
  for (int i = tid; i < ROWS * (L / 4); i += NT) {
    int r = i >> 5, c4 = i & 31;
    float4 v = ((const float4*)(x + (size_t)(k0 + r) * L))[c4];
    float* dst = &xs[r * XSS + c4 * 4];
    dst[0] = v.x; dst[1] = v.y; dst[2] = v.z; dst[3] = v.w;
  }
  for (int i = tid; i < 2 * 2 * TR * HBS; i += NT) ((short*)hb)[i] = 0;

  // per-gate exp2 prescale (g-gate feeds tanh -> -2log2e)
  const float gscale[4] = {-LOG2E, -LOG2E, -2.0f * LOG2E, -LOG2E};

  // ---- rank-1 x-projection constants (prescaled), float4 loads ----
  float An[4], Bc[4];
#pragma unroll
  for (int g = 0; g < 4; ++g) {
    int j = g * 64 + dcol;
    const float4* wr = (const float4*)(W_ih + (size_t)j * (2 * D));
    float a = 0.0f, b = b_ih[j] + b_hh[j];
#pragma unroll
    for (int e4 = 0; e4 < 16; ++e4) {
      float4 wv = wr[e4];
      float4 wn = ((const float4*)W_num)[e4];
      float4 bn = ((const float4*)b_num)[e4];
      a = fmaf(wn.x, wv.x, a); a = fmaf(wn.y, wv.y, a);
      a = fmaf(wn.z, wv.z, a); a = fmaf(wn.w, wv.w, a);
      b = fmaf(bn.x, wv.x, b); b = fmaf(bn.y, wv.y, b);
      b = fmaf(bn.z, wv.z, b); b = fmaf(bn.w, wv.w, b);
    }
    An[g] = a * gscale[g]; Bc[g] = b * gscale[g];
  }

  // ---- W_hh B-fragments (prescaled, single RTNE bf16, constant) ----
  short8 Bf[4][2];
#pragma unroll
  for (int g = 0; g < 4; ++g) {
#pragma unroll
    for (int kk = 0; kk < 2; ++kk) {
      const float4* wp = (const float4*)(W_hh + (size_t)(g * 64 + dcol) * D
                                         + kk * 32 + quad * 8);
      float wv[8];
      float4 w0 = wp[0], w1 = wp[1];
      wv[0]=w0.x; wv[1]=w0.y; wv[2]=w0.z; wv[3]=w0.w;
      wv[4]=w1.x; wv[5]=w1.y; wv[6]=w1.z; wv[7]=w1.w;
      short8 hi8;
#pragma unroll
      for (int j = 0; j < 8; ++j)
        hi8[j] = (short)f2bf_rtne(wv[j] * gscale[g]);
      Bf[g][kk] = hi8;
    }
  }

  const f4 one4 = {1.0f, 1.0f, 1.0f, 1.0f};
  const f4 m2l4 = {-2.0f * LOG2E, -2.0f * LOG2E, -2.0f * LOG2E, -2.0f * LOG2E};
  // creg4[h] = {A.r(2h), A.r(2h+1), B.r(2h), B.r(2h+1)}
  f4 creg4[2] = {{0.f,0.f,0.f,0.f}, {0.f,0.f,0.f,0.f}};
  f4 hreg4[2] = {{0.f,0.f,0.f,0.f}, {0.f,0.f,0.f,0.f}};
  __syncthreads();

  int p = 0;
  for (int t4 = 0; t4 < L; t4 += 4) {
    // 4 steps' worth of x per row in one b128 each, both streams
    float4 xqA[4], xqB[4];
#pragma unroll
    for (int r = 0; r < 4; ++r) {
      xqA[r] = *(const float4*)&xs[(quad * 4 + r) * XSS + t4];
      xqB[r] = *(const float4*)&xs[(TR + quad * 4 + r) * XSS + t4];
    }
#pragma unroll
    for (int u = 0; u < 4; ++u) {
      // both streams' A-fragments of h(t-1), issued together
      short8 aA[2], aB[2];
#pragma unroll
      for (int kk = 0; kk < 2; ++kk)
        aA[kk] = *(const short8*)&hb[0][p][c16 * HBS + kk * 32 + quad * 8];
#pragma unroll
      for (int kk = 0; kk < 2; ++kk)
        aB[kk] = *(const short8*)&hb[1][p][c16 * HBS + kk * 32 + quad * 8];

      f2 xA01 = {xqA[0][u], xqA[1][u]}, xA23 = {xqA[2][u], xqA[3][u]};
      f2 xB01 = {xqB[0][u], xqB[1][u]}, xB23 = {xqB[2][u], xqB[3][u]};

      floatx4 accA[4], accB[4];
#pragma unroll
      for (int g = 0; g < 4; ++g) {
        f2 A2 = {An[g], An[g]}, B2 = {Bc[g], Bc[g]};
        f2 iA01 = A2 * xA01 + B2;       // v_pk_fma_f32
        f2 iA23 = A2 * xA23 + B2;
        f2 iB01 = A2 * xB01 + B2;
        f2 iB23 = A2 * xB23 + B2;
        accA[g] = (floatx4){iA01.x, iA01.y, iA23.x, iA23.y};
        accB[g] = (floatx4){iB01.x, iB01.y, iB23.x, iB23.y};
      }
      // interleaved MFMA: per-accumulator order (kk0 then kk1) unchanged
#pragma unroll
      for (int kk = 0; kk < 2; ++kk) {
#pragma unroll
        for (int g = 0; g < 4; ++g) {
          accA[g] = __builtin_amdgcn_mfma_f32_16x16x32_bf16(aA[kk], Bf[g][kk], accA[g], 0, 0, 0);
          accB[g] = __builtin_amdgcn_mfma_f32_16x16x32_bf16(aB[kk], Bf[g][kk], accB[g], 0, 0, 0);
        }
      }
      // fused elementwise: f4 = {A pair, B pair}; every arith step is
      // 2 independent v_pk ops, every trans step 4 independent scalars
#pragma unroll
      for (int h = 0; h < 2; ++h) {
        f4 Gi = {accA[0][2*h], accA[0][2*h+1], accB[0][2*h], accB[0][2*h+1]};
        f4 Gf = {accA[1][2*h], accA[1][2*h+1], accB[1][2*h], accB[1][2*h+1]};
        f4 Gg = {accA[2][2*h], accA[2][2*h+1], accB[2][2*h], accB[2][2*h+1]};
        f4 Go = {accA[3][2*h], accA[3][2*h+1], accB[3][2*h], accB[3][2*h+1]};
        f4 Ei = ex2_4(Gi), Ef = ex2_4(Gf), Eg = ex2_4(Gg), Eo = ex2_4(Go);
        f4 pf = Ef + one4, pi = Ei + one4, pg = Eg + one4, mg = one4 - Eg;
        f4 pig = pi * pg;
        f4 num = creg4[h] * pig + mg * pf;
        f4 c2  = num * rcp_4(pf * pig);
        creg4[h] = c2;
        f4 Ec = ex2_4(c2 * m2l4);
        f4 po = Eo + one4, pc = Ec + one4, mc = one4 - Ec;
        f4 h2 = mc * rcp_4(po * pc);
        hreg4[h] = h2;
        int row0 = quad * 4 + 2 * h;
        short* wrA = &hb[0][p ^ 1][0];
        short* wrB = &hb[1][p ^ 1][0];
        wrA[row0 * HBS + dcol]       = (short)f2bf_rtne(h2.x);
        wrA[(row0 + 1) * HBS + dcol] = (short)f2bf_rtne(h2.y);
        wrB[row0 * HBS + dcol]       = (short)f2bf_rtne(h2.z);
        wrB[(row0 + 1) * HBS + dcol] = (short)f2bf_rtne(h2.w);
      }
      __syncthreads();
      p ^= 1;
    }
  }

  // unpack pair registers for the tail: s=0 -> .xy, s=1 -> .zw
  float creg[2][4] = {{creg4[0].x, creg4[0].y, creg4[1].x, creg4[1].y},
                      {creg4[0].z, creg4[0].w, creg4[1].z, creg4[1].w}};
  float hreg[2][4] = {{hreg4[0].x, hreg4[0].y, hreg4[1].x, hreg4[1].y},
                      {hreg4[0].z, hreg4[0].w, hreg4[1].z, hreg4[1].w}};

  // ---- tail: h_hat = h@W_aout.T+b ; f = h_hat@W_fh.T+b ; partial sums ----
  // x tile dead: xs[row][0..63] = h fp32, xs[row][64..127] = h_hat
#pragma unroll
  for (int s = 0; s < 2; ++s)
#pragma unroll
    for (int r = 0; r < 4; ++r)
      xs[(s * TR + quad * 4 + r) * XSS + dcol] = hreg[s][r];
  __syncthreads();

  float hhat[2][4];
#pragma unroll
  for (int s = 0; s < 2; ++s) {
#pragma unroll
    for (int r = 0; r < 4; ++r) {
      float a = b_aout[dcol];
      const float4* wa = (const float4*)(W_aout + (size_t)dcol * D);
      const float* hp = &xs[(s * TR + quad * 4 + r) * XSS];
#pragma unroll
      for (int e4 = 0; e4 < 16; ++e4) {
        float4 wv = wa[e4];
        a = fmaf(wv.x, hp[e4*4+0], a); a = fmaf(wv.y, hp[e4*4+1], a);
        a = fmaf(wv.z, hp[e4*4+2], a); a = fmaf(wv.w, hp[e4*4+3], a);
      }
      hhat[s][r] = a;
    }
  }
  __syncthreads();
#pragma unroll
  for (int s = 0; s < 2; ++s)
#pragma unroll
    for (int r = 0; r < 4; ++r)
      xs[(s * TR + quad * 4 + r) * XSS + 64 + dcol] = hhat[s][r];
  __syncthreads();

  float pfc = 0.0f, phs = 0.0f;
#pragma unroll
  for (int s = 0; s < 2; ++s) {
#pragma unroll
    for (int r = 0; r < 4; ++r) {
      float f = b_fh[dcol];
      const float4* wf = (const float4*)(W_fh + (size_t)dcol * D);
      const float* hp = &xs[(s * TR + quad * 4 + r) * XSS + 64];
#pragma unroll
      for (int e4 = 0; e4 < 16; ++e4) {
        float4 wv = wf[e4];
        f = fmaf(wv.x, hp[e4*4+0], f); f = fmaf(wv.y, hp[e4*4+1], f);
        f = fmaf(wv.z, hp[e4*4+2], f); f = fmaf(wv.w, hp[e4*4+3], f);
      }
      pfc = fmaf(sig_plain(f), creg[s][r], pfc);
      phs += hhat[s][r];
    }
  }
  pfc += __shfl_xor(pfc, 16); pfc += __shfl_xor(pfc, 32);
  phs += __shfl_xor(phs, 16); phs += __shfl_xor(phs, 32);
  if (quad == 0) {
    atomicAdd(acc_out + dcol, pfc);
    atomicAdd(acc_out + D + dcol, phs);
  }

  // ---- last-block finish ----
  __threadfence();
  if (tid == 0) {
    unsigned int prev = __hip_atomic_fetch_add((unsigned int*)(acc_out + 2 * D), 1u,
                                               __ATOMIC_ACQ_REL, __HIP_MEMORY_SCOPE_AGENT);
    is_last = (prev == NBLK - 1) ? 1 : 0;
  }
  __syncthreads();
  if (!is_last) return;
  __threadfence();
  if (tid < 2 * D)
    sacc[tid] = __hip_atomic_load(acc_out + tid, __ATOMIC_RELAXED, __HIP_MEMORY_SCOPE_AGENT);
  __syncthreads();
  if (tid < D) {
    const int d = tid;
    float vi = b_iouh[d], vo = b_iouh[D + d], vu = b_iouh[2 * D + d];
    for (int e = 0; e < D; ++e) {
      float hs = sacc[D + e];
      vi = fmaf(W_iouh[(size_t)d * D + e],           hs, vi);
      vo = fmaf(W_iouh[(size_t)(D + d) * D + e],     hs, vo);
      vu = fmaf(W_iouh[(size_t)(2 * D + d) * D + e], hs, vu);
    }
    float c_obj = sig_plain(vi) * tanh2(-2.0f * LOG2E * vu) + sacc[d];
    float h_obj = sig_plain(vo) * tanh2(-2.0f * LOG2E * c_obj);
    hobj[d] = h_obj;
    out[D + d] = c_obj;
  }
  __syncthreads();
  if (tid < D) {
    const int d = tid;
    float hh = b_oout[d];
    for (int e = 0; e < D; ++e) hh = fmaf(W_oout[(size_t)d * D + e], hobj[e], hh);
    out[d] = hh;
  }
}

extern "C" void kernel_launch(void* const* d_in, const int* in_sizes, int n_in,
                              void* d_out, int out_size, void* d_ws, size_t ws_size,
                              hipStream_t stream) {
  const float* x      = (const float*)d_in[0];
  const float* W_num  = (const float*)d_in[1];
  const float* b_num  = (const float*)d_in[2];
  const float* W_ih   = (const float*)d_in[3];
  const float* W_hh   = (const float*)d_in[4];
  const float* b_ih   = (const float*)d_in[5];
  const float* b_hh   = (const float*)d_in[6];
  const float* W_aout = (const float*)d_in[7];
  const float* b_aout = (const float*)d_in[8];
  const float* W_fh   = (const float*)d_in[9];
  const float* b_fh   = (const float*)d_in[10];
  const float* W_iouh = (const float*)d_in[11];
  const float* b_iouh = (const float*)d_in[12];
  const float* W_oout = (const float*)d_in[13];
  const float* b_oout = (const float*)d_in[14];
  float* acc = (float*)d_ws;
  float* out = (float*)d_out;

  hipMemsetAsync(d_ws, 0, (2 * D + 1) * sizeof(float), stream);
  lstm_main<<<NBLK, NT, 0, stream>>>(x, W_num, b_num, W_ih, W_hh, b_ih, b_hh,
                                     W_aout, b_aout, W_fh, b_fh,
                                     W_iouh, b_iouh, W_oout, b_oout, acc, out);
}